// Round 9
// baseline (267.813 us; speedup 1.0000x reference)
//
#include <hip/hip_runtime.h>
#include <stdint.h>

typedef __bf16 bf16;
typedef __bf16 bf16x8 __attribute__((ext_vector_type(8)));
typedef float  f32x4  __attribute__((ext_vector_type(4)));
typedef uint32_t u32;
typedef uint64_t u64;

#define SCALE_L2E 0.18033688011112042f   // (1/8) * log2(e)

__device__ __forceinline__ void gld_lds16(const void* gsrc, void* ldst) {
  __builtin_amdgcn_global_load_lds(
      (const __attribute__((address_space(1))) void*)gsrc,
      (__attribute__((address_space(3))) void*)ldst, 16, 0, 0);
}

__device__ __forceinline__ void pack_wr(float4 x0, float4 x1, void* dst) {
  bf16x8 vv;
  vv[0]=(bf16)x0.x; vv[1]=(bf16)x0.y; vv[2]=(bf16)x0.z; vv[3]=(bf16)x0.w;
  vv[4]=(bf16)x1.x; vv[5]=(bf16)x1.y; vv[6]=(bf16)x1.z; vv[7]=(bf16)x1.w;
  *(bf16x8*)dst = vv;                    // ds_write_b128
}

// ---------------- stage 1: prep (pack W transposed, pack mask bits) ----------------
__global__ void prep(const int* __restrict__ mask,
                     const float* __restrict__ Wq, const float* __restrict__ Wk,
                     const float* __restrict__ Wv, const float* __restrict__ Wo,
                     bf16* __restrict__ Wt, u32* __restrict__ mbits) {
  __shared__ float lds[64][65];
  const int blk = blockIdx.x;
  const int t = threadIdx.x;
  if (blk < 768) {
    // transpose-pack Wq/Wk/Wv: Wt[s][h*64+d][m] = W[h][m][d], via LDS 64x64 tile
    int s = blk >> 8, sub = blk & 255;
    int h = sub >> 4, mblk = sub & 15;
    const float* W = (s == 0) ? Wq : (s == 1) ? Wk : Wv;
    const float* src = W + h * 65536 + mblk * 4096;   // [64 m][64 d]
#pragma unroll
    for (int i = 0; i < 16; ++i) {
      int idx = t + i * 256;
      lds[idx >> 6][idx & 63] = src[idx];
    }
    __syncthreads();
    int d = t >> 2, o0 = t & 3;
#pragma unroll
    for (int oo = 0; oo < 2; ++oo) {
      int o = o0 + oo * 4;
      bf16x8 vv;
#pragma unroll
      for (int j = 0; j < 8; ++j)
        vv[j] = (bf16)lds[o * 8 + j][d];
      *(bf16x8*)&Wt[(size_t)s * 1048576 + (size_t)(h * 64 + d) * 1024 + mblk * 64 + o * 8] = vv;
    }
  } else if (blk < 832) {
    // Wo straight copy -> bf16
    int idx0 = (blk - 768) * 256 + t;
    for (int i = idx0; i < 131072; i += 16384) {
      const float4* p = (const float4*)&Wo[i * 8];
      float4 a = p[0], b = p[1];
      bf16x8 vv;
      vv[0]=(bf16)a.x; vv[1]=(bf16)a.y; vv[2]=(bf16)a.z; vv[3]=(bf16)a.w;
      vv[4]=(bf16)b.x; vv[5]=(bf16)b.y; vv[6]=(bf16)b.z; vv[7]=(bf16)b.w;
      *(bf16x8*)&Wt[3145728 + (size_t)i * 8] = vv;
    }
  } else {
    // mask int32 -> bit-packed
    int tg = (blk - 832) * 256 + t;
    for (int idx = tg; idx < 16777216; idx += 524288) {
      int m = mask[idx];
      u64 bal = __ballot(m != 0);
      if ((t & 63) == 0)
        *(u64*)&mbits[idx >> 5] = bal;
    }
  }
}

// ---------------- GEMM core: BK=32, paired-row XOR-swizzled LDS, dbuf, 32KB ----------------
// Logical tile [128 rows][32 k] bf16 as [64 pair-rows][128B = 8 x 16B blocks];
// block l of pair-row rr at physical block l^(rr&7). bf16 side staged via
// global_load_lds (linear dest, pre-swizzled global source); f32 side staged
// global->reg (issue-early) -> cvt -> ds_write_b128 (write-late, T14 split).
template<bool AF, bool BF>
__device__ __forceinline__ void gemm_core(
    const float* Af, const bf16* Ab,
    const float* Bf, const bf16* Bb,
    bf16 (&sA)[2][4096], bf16 (&sB)[2][4096],
    f32x4 (&acc)[4][4])
{
  const int tid = threadIdx.x;
  const int lane = tid & 63, w = tid >> 6;
  const int c = lane & 15, g = lane >> 4;
  const int wr = w >> 1, wc = w & 1;

  // staging coords: pair-row rr0 = tid>>3, physical block p = tid&7
  const int rr0 = tid >> 3;
  const int l0 = (tid & 7) ^ (rr0 & 7);              // logical block
  const size_t soA0 = (size_t)(2 * rr0 + (l0 >> 2)) * 1024 + (l0 & 3) * 8;
  const size_t soA1 = soA0 + (size_t)64 * 1024;      // rows +64, same block math

  // fragment read offsets (bytes within one buffer)
  const int fro = (c >> 1) * 128 + ((((c & 1) * 4 + g) ^ (c >> 1)) << 4);
  const int abase = wr * 4096 + fro;
  const int bbase = wc * 4096 + fro;

  char* dA0 = (char*)&sA[0][0];                      // buffer 0 base
  char* dB0 = (char*)&sB[0][0];

  // prologue: stage k-tile 0 into buf 0
  if constexpr (AF) {
    pack_wr(*(const float4*)(Af + soA0), *(const float4*)(Af + soA0 + 4), dA0 + tid * 16);
    pack_wr(*(const float4*)(Af + soA1), *(const float4*)(Af + soA1 + 4), dA0 + 4096 + tid * 16);
  } else {
    gld_lds16(Ab + soA0, dA0 + tid * 16);
    gld_lds16(Ab + soA1, dA0 + 4096 + tid * 16);
  }
  if constexpr (BF) {
    pack_wr(*(const float4*)(Bf + soA0), *(const float4*)(Bf + soA0 + 4), dB0 + tid * 16);
    pack_wr(*(const float4*)(Bf + soA1), *(const float4*)(Bf + soA1 + 4), dB0 + 4096 + tid * 16);
  } else {
    gld_lds16(Bb + soA0, dB0 + tid * 16);
    gld_lds16(Bb + soA1, dB0 + 4096 + tid * 16);
  }

  for (int k0 = 0; k0 < 1024; k0 += 32) {
    __syncthreads();
    const int cb = (k0 >> 5) & 1, nb = cb ^ 1;
    char* dAn = (char*)&sA[nb][0];
    char* dBn = (char*)&sB[nb][0];

    // issue next-tile loads (f32 -> regs now, written after MFMA; bf16 -> gld_lds)
    float4 ra0, ra1, ra2, ra3, rb0, rb1, rb2, rb3;
    if (k0 < 992) {
      if constexpr (AF) {
        ra0 = *(const float4*)(Af + soA0 + k0 + 32);
        ra1 = *(const float4*)(Af + soA0 + k0 + 36);
        ra2 = *(const float4*)(Af + soA1 + k0 + 32);
        ra3 = *(const float4*)(Af + soA1 + k0 + 36);
      } else {
        gld_lds16(Ab + soA0 + k0 + 32, dAn + tid * 16);
        gld_lds16(Ab + soA1 + k0 + 32, dAn + 4096 + tid * 16);
      }
      if constexpr (BF) {
        rb0 = *(const float4*)(Bf + soA0 + k0 + 32);
        rb1 = *(const float4*)(Bf + soA0 + k0 + 36);
        rb2 = *(const float4*)(Bf + soA1 + k0 + 32);
        rb3 = *(const float4*)(Bf + soA1 + k0 + 36);
      } else {
        gld_lds16(Bb + soA0 + k0 + 32, dBn + tid * 16);
        gld_lds16(Bb + soA1 + k0 + 32, dBn + 4096 + tid * 16);
      }
    }

    // MFMA on current buffer
    const char* a8 = (const char*)&sA[cb][0] + abase;
    const char* b8 = (const char*)&sB[cb][0] + bbase;
    bf16x8 af[4], bfr[4];
#pragma unroll
    for (int m = 0; m < 4; ++m)
      af[m] = *(const bf16x8*)(a8 + m * 1024);
#pragma unroll
    for (int n = 0; n < 4; ++n)
      bfr[n] = *(const bf16x8*)(b8 + n * 1024);
#pragma unroll
    for (int m = 0; m < 4; ++m)
#pragma unroll
      for (int n = 0; n < 4; ++n)
        acc[m][n] = __builtin_amdgcn_mfma_f32_16x16x32_bf16(af[m], bfr[n], acc[m][n], 0, 0, 0);

    // write-late: staged f32 regs -> LDS (loads have had the MFMA block to land)
    if (k0 < 992) {
      if constexpr (AF) {
        pack_wr(ra0, ra1, dAn + tid * 16);
        pack_wr(ra2, ra3, dAn + 4096 + tid * 16);
      }
      if constexpr (BF) {
        pack_wr(rb0, rb1, dBn + tid * 16);
        pack_wr(rb2, rb3, dBn + 4096 + tid * 16);
      }
    }
  }
}

// fused projections: wgs 0..1023 -> Q|K (A = f32 q|k), wgs 1024..1535 -> Vt (B = f32 v)
__global__ __launch_bounds__(256, 4)
void proj_fused(const float* __restrict__ q, const float* __restrict__ k,
                const float* __restrict__ v, const bf16* __restrict__ Wt,
                bf16* __restrict__ Qp, bf16* __restrict__ Kp, bf16* __restrict__ Vt) {
  __shared__ bf16 sA[2][4096];
  __shared__ bf16 sB[2][4096];
  const int wg = blockIdx.x;
  const int lane = threadIdx.x & 63, w = threadIdx.x >> 6;
  const int c = lane & 15, g = lane >> 4;
  const int wr = w >> 1, wc = w & 1;
  f32x4 acc[4][4] = {};

  if (wg < 1024) {
    int swz = (wg & 7) * 128 + (wg >> 3);
    int bx = swz & 7, by = swz >> 3;
    const int row0 = by * 128, col0 = bx * 128;
    const int isK = (row0 >= 8192);
    const float* Af = isK ? (k + (size_t)(row0 - 8192) * 1024)
                          : (q + (size_t)row0 * 1024);
    const bf16* Bb = Wt + (isK ? 1048576 : 0) + (size_t)col0 * 1024;

    gemm_core<true, false>(Af, nullptr, nullptr, Bb, sA, sB, acc);

    float csc = isK ? 1.0f : SCALE_L2E;
    bf16* dst = isK ? Kp : Qp;
#pragma unroll
    for (int m = 0; m < 4; ++m) {
      int row_base = (row0 & 8191) + wr * 64 + m * 16 + g * 4;
#pragma unroll
      for (int n = 0; n < 4; ++n) {
        int col = col0 + wc * 64 + n * 16 + c;
#pragma unroll
        for (int r = 0; r < 4; ++r) {
          int row = row_base + r;
          int b = row >> 11, l = row & 2047, h = col >> 6, d = col & 63;
          dst[(((size_t)(b * 16 + h) * 2048 + l) << 6) + d] = (bf16)(acc[m][n][r] * csc);
        }
      }
    }
  } else {
    int w2 = wg - 1024;
    int bz = w2 >> 7, rem = w2 & 127;
    int swz = (rem & 7) * 16 + (rem >> 3);
    int bx = swz & 15, by = swz >> 4;
    const int row0 = by * 128, col0 = bx * 128;
    const bf16* Ab = Wt + 2097152 + (size_t)row0 * 1024;
    const float* Bf = v + (size_t)bz * 2097152 + (size_t)col0 * 1024;

    gemm_core<false, true>(nullptr, Ab, Bf, nullptr, sA, sB, acc);

#pragma unroll
    for (int m = 0; m < 4; ++m) {
      int row_base = row0 + wr * 64 + m * 16 + g * 4;
#pragma unroll
      for (int n = 0; n < 4; ++n) {
        int col = col0 + wc * 64 + n * 16 + c;
#pragma unroll
        for (int r = 0; r < 4; ++r)
          Vt[((size_t)(bz * 1024 + row_base + r)) * 2048 + col] = (bf16)acc[m][n][r];
      }
    }
  }
}

// output projection: out = X . Wo^T + b (f32)
__global__ __launch_bounds__(256, 4)
void gemm_out(const bf16* __restrict__ X, const bf16* __restrict__ Wot,
              float* __restrict__ out, const float* __restrict__ bias) {
  __shared__ bf16 sA[2][4096];
  __shared__ bf16 sB[2][4096];
  int lin = blockIdx.y * 8 + blockIdx.x;
  int swz = (lin & 7) * 64 + (lin >> 3);
  int bx = swz & 7, by = swz >> 3;
  const int row0 = by * 128, col0 = bx * 128;
  const int lane = threadIdx.x & 63, w = threadIdx.x >> 6;
  const int c = lane & 15, g = lane >> 4;
  const int wr = w >> 1, wc = w & 1;
  f32x4 acc[4][4] = {};

  gemm_core<false, false>(nullptr, X + (size_t)row0 * 1024,
                          nullptr, Wot + (size_t)col0 * 1024, sA, sB, acc);

#pragma unroll
  for (int m = 0; m < 4; ++m) {
    int row_base = row0 + wr * 64 + m * 16 + g * 4;
#pragma unroll
    for (int n = 0; n < 4; ++n) {
      int col = col0 + wc * 64 + n * 16 + c;
      float bv = bias[col];
#pragma unroll
      for (int r = 0; r < 4; ++r)
        out[(size_t)(row_base + r) * 1024 + col] = acc[m][n][r] + bv;
    }
  }
}

// ---------------- stage 3: flash attention, KVBLK=32, 24KB LDS (R8 exact) ----------------
__global__ __launch_bounds__(256, 4)
void attn_fwd(const bf16* __restrict__ Qp, const bf16* __restrict__ Kp,
              const bf16* __restrict__ Vt, const u32* __restrict__ mbits,
              bf16* __restrict__ X) {
  int lin = blockIdx.y * 16 + blockIdx.x;
  int swz = (lin & 7) * 128 + (lin >> 3);
  int qt = swz & 15, bh = swz >> 4;
  int b = bh >> 4, h = bh & 15;
  int q0 = qt * 128;

  const int tid = threadIdx.x;
  const int lane = tid & 63, w = tid >> 6;
  const int c = lane & 15, g = lane >> 4;

  __shared__ char smem[24576];
  char* sKV = smem;                        // 2 slots x {K 4KB | V 4KB}
  char* sPw = smem + 16384 + w * 2048;     // per-wave P: [32 q][32 keys] bf16, paired rows

  const int c7 = c & 7;
  const int ko0 = c * 128 + ((g ^ c7) << 4);
  const int ko1 = c * 128 + (((4 + g) ^ c7) << 4);
  const int pr_off = (c >> 1) * 128 + ((((c & 1) * 4 + g) ^ (c >> 1)) << 4);
  int pwo[2];
#pragma unroll
  for (int nk = 0; nk < 2; ++nk)
    pwo[nk] = (c >> 1) * 128 + ((((c & 1) * 4 + nk * 2 + (g >> 1)) ^ (c >> 1)) << 4) + (g & 1) * 8;

  const int kr_ = tid >> 3, kb_ = tid & 7;
  const int dK = kr_ * 128 + ((kb_ ^ (kr_ & 7)) << 4);
  const int vd_ = tid >> 2, vk_ = tid & 3;
  const int dV = 4096 + (vd_ >> 1) * 128 + (((((vd_ & 1) << 2) + vk_) ^ ((vd_ >> 1) & 7)) << 4);
  const bf16* gK = Kp + (size_t)bh * 131072 + kr_ * 64 + kb_ * 8;
  const bf16* gV = Vt + ((size_t)(b * 1024 + h * 64 + vd_)) * 2048 + vk_ * 8;

  const bf16* Qbase = Qp + ((size_t)bh * 2048) * 64;
  bf16x8 qf[2][2];
#pragma unroll
  for (int nq = 0; nq < 2; ++nq) {
    int qg = q0 + w * 32 + nq * 16 + c;
#pragma unroll
    for (int kk = 0; kk < 2; ++kk)
      qf[nq][kk] = *(const bf16x8*)&Qbase[(size_t)qg * 64 + kk * 32 + g * 8];
  }

  bf16x8 onesv;
#pragma unroll
  for (int i = 0; i < 8; ++i) onesv[i] = (bf16)1.0f;

  const u32* Mrow0 = mbits + ((size_t)b * 2048 + (q0 + w * 32 + c)) * 64;
  const u32* Mrow1 = mbits + ((size_t)b * 2048 + (q0 + w * 32 + 16 + c)) * 64;

  f32x4 oacc[4][2] = {};                  // [md][nq] : O^T[d][q]
  f32x4 dacc[2] = {};

  {
    uint4 kr = *(const uint4*)gK;
    uint4 vr = *(const uint4*)gV;
    *(uint4*)(sKV + dK) = kr;
    *(uint4*)(sKV + dV) = vr;
  }
  u32 mw0 = Mrow0[0], mw1 = Mrow1[0];

  for (int t = 0; t < 64; ++t) {
    __syncthreads();
    const char* kbuf = sKV + ((t & 1) << 13);

    uint4 kr, vr;
    u32 mn0 = 0, mn1 = 0;
    if (t < 63) {
      kr = *(const uint4*)(gK + (size_t)(t + 1) * 2048);
      vr = *(const uint4*)(gV + (size_t)(t + 1) * 32);
      mn0 = Mrow0[t + 1];
      mn1 = Mrow1[t + 1];
    }

    // QK^T (swapped): St[key][q], 32 keys
    f32x4 st[2][2] = {};
    __builtin_amdgcn_s_setprio(1);
#pragma unroll
    for (int nk = 0; nk < 2; ++nk) {
      bf16x8 kfa = *(const bf16x8*)(kbuf + ko0 + nk * 2048);
      st[nk][0] = __builtin_amdgcn_mfma_f32_16x16x32_bf16(kfa, qf[0][0], st[nk][0], 0, 0, 0);
      st[nk][1] = __builtin_amdgcn_mfma_f32_16x16x32_bf16(kfa, qf[1][0], st[nk][1], 0, 0, 0);
      bf16x8 kfb = *(const bf16x8*)(kbuf + ko1 + nk * 2048);
      st[nk][0] = __builtin_amdgcn_mfma_f32_16x16x32_bf16(kfb, qf[0][1], st[nk][0], 0, 0, 0);
      st[nk][1] = __builtin_amdgcn_mfma_f32_16x16x32_bf16(kfb, qf[1][1], st[nk][1], 0, 0, 0);
    }
    __builtin_amdgcn_s_setprio(0);

    // static-m softmax: p = mask ? exp2(st) : 0 ; pack bf16 quads -> LDS
#pragma unroll
    for (int nq = 0; nq < 2; ++nq) {
      u32 ms = (nq ? mw1 : mw0) >> (4 * g);
#pragma unroll
      for (int nk = 0; nk < 2; ++nk) {
        const int bs = nk * 16;
        float e0 = __builtin_amdgcn_exp2f(st[nk][nq][0]);
        float e1 = __builtin_amdgcn_exp2f(st[nk][nq][1]);
        float e2 = __builtin_amdgcn_exp2f(st[nk][nq][2]);
        float e3 = __builtin_amdgcn_exp2f(st[nk][nq][3]);
        e0 = (ms & (1u << (bs + 0))) ? e0 : 0.f;
        e1 = (ms & (1u << (bs + 1))) ? e1 : 0.f;
        e2 = (ms & (1u << (bs + 2))) ? e2 : 0.f;
        e3 = (ms & (1u << (bs + 3))) ? e3 : 0.f;
        union { bf16 hh[4]; uint2 dd; } pk;
        pk.hh[0] = (bf16)e0; pk.hh[1] = (bf16)e1;
        pk.hh[2] = (bf16)e2; pk.hh[3] = (bf16)e3;
        *(uint2*)(sPw + pwo[nk] + nq * 1024) = pk.dd;
      }
    }

    // PV: O^T[d][q] += Vt . P^T ; denominator via mfma(ones, P)
    __builtin_amdgcn_s_setprio(1);
    {
      bf16x8 pf0 = *(const bf16x8*)(sPw + pr_off);
      bf16x8 pf1 = *(const bf16x8*)(sPw + pr_off + 1024);
      dacc[0] = __builtin_amdgcn_mfma_f32_16x16x32_bf16(onesv, pf0, dacc[0], 0, 0, 0);
      dacc[1] = __builtin_amdgcn_mfma_f32_16x16x32_bf16(onesv, pf1, dacc[1], 0, 0, 0);
#pragma unroll
      for (int md = 0; md < 4; ++md) {
        bf16x8 vf = *(const bf16x8*)(kbuf + 4096 + pr_off + md * 1024);
        oacc[md][0] = __builtin_amdgcn_mfma_f32_16x16x32_bf16(vf, pf0, oacc[md][0], 0, 0, 0);
        oacc[md][1] = __builtin_amdgcn_mfma_f32_16x16x32_bf16(vf, pf1, oacc[md][1], 0, 0, 0);
      }
    }
    __builtin_amdgcn_s_setprio(0);

    if (t < 63) {
      char* nbuf = sKV + (((t + 1) & 1) << 13);
      *(uint4*)(nbuf + dK) = kr;
      *(uint4*)(nbuf + dV) = vr;
    }
    mw0 = mn0; mw1 = mn1;
  }

  float inv0 = 1.f / dacc[0][0];
  float inv1 = 1.f / dacc[1][0];

  // epilogue: O^T -> LDS transpose -> coalesced bf16 write
  __syncthreads();
  char* Xl = smem;
#pragma unroll
  for (int nq = 0; nq < 2; ++nq) {
    float inv = nq ? inv1 : inv0;
    int ql = w * 32 + nq * 16 + c;
#pragma unroll
    for (int md = 0; md < 4; ++md)
#pragma unroll
      for (int r = 0; r < 4; ++r) {
        int d = md * 16 + g * 4 + r;
        int blk = d >> 3, off = d & 7;
        *(bf16*)(Xl + ql * 128 + ((blk ^ (ql & 7)) << 4) + off * 2) =
            (bf16)(oacc[md][nq][r] * inv);
      }
  }
  __syncthreads();
#pragma unroll
  for (int i = 0; i < 4; ++i) {
    int u = i * 256 + tid;
    int row = u >> 3, blk = u & 7;
    uint4 xv = *(const uint4*)(Xl + row * 128 + ((blk ^ (row & 7)) << 4));
    *(uint4*)&X[(size_t)(b * 2048 + q0 + row) * 1024 + h * 64 + blk * 8] = xv;
  }
}

// ---------------- launch ----------------

extern "C" void kernel_launch(void* const* d_in, const int* in_sizes, int n_in,
                              void* d_out, int out_size, void* d_ws, size_t ws_size,
                              hipStream_t stream) {
  const float* q    = (const float*)d_in[0];
  const float* k    = (const float*)d_in[1];
  const float* v    = (const float*)d_in[2];
  const int*   mask = (const int*)d_in[3];
  const float* Wq   = (const float*)d_in[4];
  const float* Wk   = (const float*)d_in[5];
  const float* Wv   = (const float*)d_in[6];
  const float* Wo   = (const float*)d_in[7];
  const float* Wb   = (const float*)d_in[8];

  char* ws = (char*)d_ws;
  bf16* Wt  = (bf16*)(ws + 50331648);      // 8 MB (4 packed 1024x1024)
  bf16* Qp  = (bf16*)(ws + 58720256);
  bf16* Kp  = (bf16*)(ws + 75497472);
  bf16* Vt  = (bf16*)(ws + 92274688);
  bf16* Xb  = (bf16*)(ws + 109051904);
  u32*  mb  = (u32*) (ws + 125829120);     // 2 MB bitmask

  prep<<<dim3(2880, 1, 1), 256, 0, stream>>>(mask, Wq, Wk, Wv, Wo, Wt, mb);

  proj_fused<<<dim3(1536, 1, 1), 256, 0, stream>>>(q, k, v, Wt, Qp, Kp, Vt);

  attn_fwd<<<dim3(16, 64, 1), 256, 0, stream>>>(Qp, Kp, Vt, mb, Xb);

  gemm_out<<<dim3(8, 64, 1), 256, 0, stream>>>(Xb, Wt + 3145728, (float*)d_out, Wb);
}

// Round 10
// 243.106 us; speedup vs baseline: 1.1016x; 1.1016x over previous
//
#include <hip/hip_runtime.h>
#include <stdint.h>

typedef __bf16 bf16;
typedef __bf16 bf16x8 __attribute__((ext_vector_type(8)));
typedef float  f32x4  __attribute__((ext_vector_type(4)));
typedef uint32_t u32;
typedef uint64_t u64;

#define SCALE_L2E 0.18033688011112042f   // (1/8) * log2(e)

__device__ __forceinline__ void gld_lds16(const void* gsrc, void* ldst) {
  __builtin_amdgcn_global_load_lds(
      (const __attribute__((address_space(1))) void*)gsrc,
      (__attribute__((address_space(3))) void*)ldst, 16, 0, 0);
}

// ---------------- stage 1: fused prep (cvt q/k/v, pack W, pack mask) ----------------
__global__ void prep(const float* __restrict__ q, const float* __restrict__ k,
                     const float* __restrict__ v, const int* __restrict__ mask,
                     const float* __restrict__ Wq, const float* __restrict__ Wk,
                     const float* __restrict__ Wv, const float* __restrict__ Wo,
                     bf16* __restrict__ qkv, bf16* __restrict__ Wt, u32* __restrict__ mbits) {
  __shared__ float lds[64][65];
  const int z = blockIdx.z;
  const int t = threadIdx.x;
  const int tg = blockIdx.x * 256 + t;                  // 0..524287
  if (z < 3) {
    const float* in = (z == 0) ? q : (z == 1) ? k : v;
    bf16* o = qkv + (size_t)z * 8388608;
#pragma unroll
    for (int it = 0; it < 2; ++it) {
      int i = tg + it * 524288;
      const float4* p = (const float4*)(in + (size_t)i * 8);
      float4 a = p[0], b = p[1];
      bf16x8 vv;
      vv[0]=(bf16)a.x; vv[1]=(bf16)a.y; vv[2]=(bf16)a.z; vv[3]=(bf16)a.w;
      vv[4]=(bf16)b.x; vv[5]=(bf16)b.y; vv[6]=(bf16)b.z; vv[7]=(bf16)b.w;
      *(bf16x8*)(o + (size_t)i * 8) = vv;
    }
  } else if (z == 3) {
    const int blk = blockIdx.x;
    if (blk < 768) {
      // transpose-pack Wq/Wk/Wv: Wt[s][h*64+d][m] = W[h][m][d], via LDS 64x64 tile
      int s = blk >> 8, sub = blk & 255;
      int h = sub >> 4, mblk = sub & 15;
      const float* W = (s == 0) ? Wq : (s == 1) ? Wk : Wv;
      const float* src = W + h * 65536 + mblk * 4096;   // [64 m][64 d]
#pragma unroll
      for (int i = 0; i < 16; ++i) {
        int idx = t + i * 256;
        lds[idx >> 6][idx & 63] = src[idx];
      }
      __syncthreads();
      int d = t >> 2, o0 = t & 3;
#pragma unroll
      for (int oo = 0; oo < 2; ++oo) {
        int o = o0 + oo * 4;
        bf16x8 vv;
#pragma unroll
        for (int j = 0; j < 8; ++j)
          vv[j] = (bf16)lds[o * 8 + j][d];
        *(bf16x8*)&Wt[(size_t)s * 1048576 + (size_t)(h * 64 + d) * 1024 + mblk * 64 + o * 8] = vv;
      }
    } else if (blk < 832) {
      // Wo straight copy -> bf16
      int idx0 = (blk - 768) * 256 + t;
      for (int i = idx0; i < 131072; i += 16384) {
        const float4* p = (const float4*)&Wo[i * 8];
        float4 a = p[0], b = p[1];
        bf16x8 vv;
        vv[0]=(bf16)a.x; vv[1]=(bf16)a.y; vv[2]=(bf16)a.z; vv[3]=(bf16)a.w;
        vv[4]=(bf16)b.x; vv[5]=(bf16)b.y; vv[6]=(bf16)b.z; vv[7]=(bf16)b.w;
        *(bf16x8*)&Wt[3145728 + (size_t)i * 8] = vv;
      }
    }
  } else {
    for (int idx = tg; idx < 16777216; idx += 524288) {
      int m = mask[idx];
      u64 bal = __ballot(m != 0);
      if ((t & 63) == 0)
        *(u64*)&mbits[idx >> 5] = bal;
    }
  }
}

// ---------------- GEMM core: BK=32, paired-row XOR-swizzled LDS, dbuf, 32KB ----------------
#define GEMM_CORE(Ap_, Bp_)                                                    \
  __shared__ bf16 sA[2][4096];                                                 \
  __shared__ bf16 sB[2][4096];                                                 \
  const int tid = threadIdx.x;                                                 \
  const int lane = tid & 63, w = tid >> 6;                                     \
  const int c = lane & 15, g = lane >> 4;                                      \
  const int wr = w >> 1, wc = w & 1;                                           \
  const int rr0 = tid >> 3, p0_ = tid & 7;                                     \
  const int l0 = p0_ ^ (rr0 & 7);                                              \
  const size_t so0 = (size_t)(2 * rr0 + (l0 >> 2)) * 1024 + (l0 & 3) * 8;      \
  const int rr1 = (256 + tid) >> 3, p1_ = tid & 7;                             \
  const int l1 = p1_ ^ (rr1 & 7);                                              \
  const size_t so1 = (size_t)(2 * rr1 + (l1 >> 2)) * 1024 + (l1 & 3) * 8;      \
  const bf16* As0 = (Ap_) + so0;                                               \
  const bf16* As1 = (Ap_) + so1;                                               \
  const bf16* Bs0 = (Bp_) + so0;                                               \
  const bf16* Bs1 = (Bp_) + so1;                                               \
  const int fro = (c >> 1) * 128 + ((((c & 1) * 4 + g) ^ (c >> 1)) << 4);      \
  const int abase = wr * 4096 + fro;                                           \
  const int bbase = wc * 4096 + fro;                                           \
  f32x4 acc[4][4] = {};                                                        \
  gld_lds16(As0, (char*)&sA[0][0] + tid * 16);                                 \
  gld_lds16(As1, (char*)&sA[0][0] + 4096 + tid * 16);                          \
  gld_lds16(Bs0, (char*)&sB[0][0] + tid * 16);                                 \
  gld_lds16(Bs1, (char*)&sB[0][0] + 4096 + tid * 16);                          \
  for (int k0 = 0; k0 < 1024; k0 += 32) {                                      \
    __syncthreads();                                                           \
    int cb = (k0 >> 5) & 1, nb = cb ^ 1;                                       \
    if (k0 < 992) {                                                            \
      gld_lds16(As0 + k0 + 32, (char*)&sA[nb][0] + tid * 16);                  \
      gld_lds16(As1 + k0 + 32, (char*)&sA[nb][0] + 4096 + tid * 16);           \
      gld_lds16(Bs0 + k0 + 32, (char*)&sB[nb][0] + tid * 16);                  \
      gld_lds16(Bs1 + k0 + 32, (char*)&sB[nb][0] + 4096 + tid * 16);           \
    }                                                                          \
    const char* a8 = (const char*)&sA[cb][0] + abase;                          \
    const char* b8 = (const char*)&sB[cb][0] + bbase;                          \
    bf16x8 af[4], bfr[4];                                                      \
    _Pragma("unroll")                                                          \
    for (int m = 0; m < 4; ++m)                                                \
      af[m] = *(const bf16x8*)(a8 + m * 1024);                                 \
    _Pragma("unroll")                                                          \
    for (int n = 0; n < 4; ++n)                                                \
      bfr[n] = *(const bf16x8*)(b8 + n * 1024);                                \
    _Pragma("unroll")                                                          \
    for (int m = 0; m < 4; ++m)                                                \
      _Pragma("unroll")                                                        \
      for (int n = 0; n < 4; ++n)                                              \
        acc[m][n] = __builtin_amdgcn_mfma_f32_16x16x32_bf16(af[m], bfr[n], acc[m][n], 0, 0, 0); \
  }

// fused projections: wgs 0..1023 -> Q|K (M=16384 over qb|kb), wgs 1024..1535 -> Vt
__global__ __launch_bounds__(256, 4)
void proj_fused(const bf16* __restrict__ qkv, const bf16* __restrict__ Wt,
                bf16* __restrict__ Qp, bf16* __restrict__ Kp, bf16* __restrict__ Vt) {
  const int wg = blockIdx.x;
  const bf16* Ap;
  const bf16* Bp;
  int row0, col0, stage;
  if (wg < 1024) {
    int swz = (wg & 7) * 128 + (wg >> 3);
    int bx = swz & 7, by = swz >> 3;
    row0 = by * 128; col0 = bx * 128;
    stage = (row0 >= 8192) ? 1 : 0;                  // 0=Q, 1=K
    Ap = qkv + (size_t)row0 * 1024;                  // qb|kb contiguous
    Bp = Wt + (stage ? 1048576 : 0) + (size_t)col0 * 1024;
  } else {
    int w2 = wg - 1024;
    int bz = w2 >> 7, rem = w2 & 127;
    int swz = (rem & 7) * 16 + (rem >> 3);
    int bx = swz & 15, by = swz >> 4;
    row0 = by * 128; col0 = bx * 128;
    stage = 2 + bz;                                   // Vt, batch bz
    Ap = Wt + 2097152 + (size_t)row0 * 1024;
    Bp = qkv + 16777216 + (size_t)bz * 2097152 + (size_t)col0 * 1024;  // vb
  }

  GEMM_CORE(Ap, Bp)

  if (stage <= 1) {
    float csc = stage ? 1.0f : SCALE_L2E;
    bf16* dst = stage ? Kp : Qp;
#pragma unroll
    for (int m = 0; m < 4; ++m) {
      int row_base = (row0 & 8191) + wr * 64 + m * 16 + g * 4;
#pragma unroll
      for (int n = 0; n < 4; ++n) {
        int col = col0 + wc * 64 + n * 16 + c;
#pragma unroll
        for (int r = 0; r < 4; ++r) {
          int row = row_base + r;
          int b = row >> 11, l = row & 2047, h = col >> 6, d = col & 63;
          dst[(((size_t)(b * 16 + h) * 2048 + l) << 6) + d] = (bf16)(acc[m][n][r] * csc);
        }
      }
    }
  } else {
    int bz = stage - 2;
#pragma unroll
    for (int m = 0; m < 4; ++m) {
      int row_base = row0 + wr * 64 + m * 16 + g * 4;
#pragma unroll
      for (int n = 0; n < 4; ++n) {
        int col = col0 + wc * 64 + n * 16 + c;
#pragma unroll
        for (int r = 0; r < 4; ++r)
          Vt[((size_t)(bz * 1024 + row_base + r)) * 2048 + col] = (bf16)acc[m][n][r];
      }
    }
  }
}

// output projection: out = X . Wo^T + b (f32)
__global__ __launch_bounds__(256, 4)
void gemm_out(const bf16* __restrict__ X, const bf16* __restrict__ Wot,
              float* __restrict__ out, const float* __restrict__ bias) {
  int lin = blockIdx.y * 8 + blockIdx.x;
  int swz = (lin & 7) * 64 + (lin >> 3);
  int bx = swz & 7, by = swz >> 3;
  const int row0 = by * 128, col0 = bx * 128;
  const bf16* Apx = X + (size_t)row0 * 1024;
  const bf16* Bpx = Wot + (size_t)col0 * 1024;

  GEMM_CORE(Apx, Bpx)

#pragma unroll
  for (int m = 0; m < 4; ++m) {
    int row_base = row0 + wr * 64 + m * 16 + g * 4;
#pragma unroll
    for (int n = 0; n < 4; ++n) {
      int col = col0 + wc * 64 + n * 16 + c;
      float bv = bias[col];
#pragma unroll
      for (int r = 0; r < 4; ++r)
        out[(size_t)(row_base + r) * 1024 + col] = acc[m][n][r] + bv;
    }
  }
}

// ---------------- stage 3: flash attention, KVBLK=32, LUT mask-AND softmax ----------------
__global__ __launch_bounds__(256, 4)
void attn_fwd(const bf16* __restrict__ Qp, const bf16* __restrict__ Kp,
              const bf16* __restrict__ Vt, const u32* __restrict__ mbits,
              bf16* __restrict__ X) {
  int lin = blockIdx.y * 16 + blockIdx.x;
  int swz = (lin & 7) * 128 + (lin >> 3);
  int qt = swz & 15, bh = swz >> 4;
  int b = bh >> 4, h = bh & 15;
  int q0 = qt * 128;

  const int tid = threadIdx.x;
  const int lane = tid & 63, w = tid >> 6;
  const int c = lane & 15, g = lane >> 4;

  __shared__ char smem[24704];
  char* sKV = smem;                        // 2 slots x {K 4KB | V 4KB}
  char* sPw = smem + 16384 + w * 2048;     // per-wave P: [32 q][32 keys] bf16, paired rows
  char* sLut = smem + 24576;               // 16-entry nibble -> uint2 AND-mask LUT (128B)

  const int c7 = c & 7;
  const int ko0 = c * 128 + ((g ^ c7) << 4);
  const int ko1 = c * 128 + (((4 + g) ^ c7) << 4);
  const int pr_off = (c >> 1) * 128 + ((((c & 1) * 4 + g) ^ (c >> 1)) << 4);
  int pwo[2];
#pragma unroll
  for (int nk = 0; nk < 2; ++nk)
    pwo[nk] = (c >> 1) * 128 + ((((c & 1) * 4 + nk * 2 + (g >> 1)) ^ (c >> 1)) << 4) + (g & 1) * 8;

  const int kr_ = tid >> 3, kb_ = tid & 7;
  const int dK = kr_ * 128 + ((kb_ ^ (kr_ & 7)) << 4);
  const int vd_ = tid >> 2, vk_ = tid & 3;
  const int dV = 4096 + (vd_ >> 1) * 128 + (((((vd_ & 1) << 2) + vk_) ^ ((vd_ >> 1) & 7)) << 4);
  const bf16* gK = Kp + (size_t)bh * 131072 + kr_ * 64 + kb_ * 8;
  const bf16* gV = Vt + ((size_t)(b * 1024 + h * 64 + vd_)) * 2048 + vk_ * 8;

  const bf16* Qbase = Qp + ((size_t)bh * 2048) * 64;
  bf16x8 qf[2][2];
#pragma unroll
  for (int nq = 0; nq < 2; ++nq) {
    int qg = q0 + w * 32 + nq * 16 + c;
#pragma unroll
    for (int kk = 0; kk < 2; ++kk)
      qf[nq][kk] = *(const bf16x8*)&Qbase[(size_t)qg * 64 + kk * 32 + g * 8];
  }

  bf16x8 onesv;
#pragma unroll
  for (int i = 0; i < 8; ++i) onesv[i] = (bf16)1.0f;

  const u32* Mrow0 = mbits + ((size_t)b * 2048 + (q0 + w * 32 + c)) * 64;
  const u32* Mrow1 = mbits + ((size_t)b * 2048 + (q0 + w * 32 + 16 + c)) * 64;
  const int pos0 = 4 * g;        // nibble position for nk=0 (bits 4g..4g+3)
  const int pos1 = 16 + 4 * g;   // nk=1

  f32x4 oacc[4][2] = {};                  // [md][nq] : O^T[d][q]
  f32x4 dacc[2] = {};

  // prologue: LUT + tile 0 -> LDS slot 0
  if (tid < 16) {
    u32 n = tid;
    uint2 e;
    e.x = ((n & 1) ? 0xFFFFu : 0u) | ((n & 2) ? 0xFFFF0000u : 0u);
    e.y = ((n & 4) ? 0xFFFFu : 0u) | ((n & 8) ? 0xFFFF0000u : 0u);
    *(uint2*)(sLut + n * 8) = e;
  }
  {
    uint4 kr = *(const uint4*)gK;
    uint4 vr = *(const uint4*)gV;
    *(uint4*)(sKV + dK) = kr;
    *(uint4*)(sKV + dV) = vr;
  }
  u32 mw0 = Mrow0[0], mw1 = Mrow1[0];

  for (int t = 0; t < 64; ++t) {
    __syncthreads();
    const char* kbuf = sKV + ((t & 1) << 13);

    // LUT AND-masks for this tile (mask words known since last iter; lgkm hides under QK)
    uint2 lm00 = *(const uint2*)(sLut + ((mw0 >> pos0) & 15u) * 8);
    uint2 lm01 = *(const uint2*)(sLut + ((mw0 >> pos1) & 15u) * 8);
    uint2 lm10 = *(const uint2*)(sLut + ((mw1 >> pos0) & 15u) * 8);
    uint2 lm11 = *(const uint2*)(sLut + ((mw1 >> pos1) & 15u) * 8);

    uint4 kr, vr;
    u32 mn0 = 0, mn1 = 0;
    if (t < 63) {
      kr = *(const uint4*)(gK + (size_t)(t + 1) * 2048);
      vr = *(const uint4*)(gV + (size_t)(t + 1) * 32);
      mn0 = Mrow0[t + 1];
      mn1 = Mrow1[t + 1];
    }

    // QK^T (swapped): St[key][q], 32 keys
    f32x4 st[2][2] = {};
    __builtin_amdgcn_s_setprio(1);
#pragma unroll
    for (int nk = 0; nk < 2; ++nk) {
      bf16x8 kfa = *(const bf16x8*)(kbuf + ko0 + nk * 2048);
      st[nk][0] = __builtin_amdgcn_mfma_f32_16x16x32_bf16(kfa, qf[0][0], st[nk][0], 0, 0, 0);
      st[nk][1] = __builtin_amdgcn_mfma_f32_16x16x32_bf16(kfa, qf[1][0], st[nk][1], 0, 0, 0);
      bf16x8 kfb = *(const bf16x8*)(kbuf + ko1 + nk * 2048);
      st[nk][0] = __builtin_amdgcn_mfma_f32_16x16x32_bf16(kfb, qf[0][1], st[nk][0], 0, 0, 0);
      st[nk][1] = __builtin_amdgcn_mfma_f32_16x16x32_bf16(kfb, qf[1][1], st[nk][1], 0, 0, 0);
    }
    __builtin_amdgcn_s_setprio(0);

    // static-m softmax: p = exp2(st); mask via bitwise AND on packed bf16
#pragma unroll
    for (int nq = 0; nq < 2; ++nq) {
#pragma unroll
      for (int nk = 0; nk < 2; ++nk) {
        float e0 = __builtin_amdgcn_exp2f(st[nk][nq][0]);
        float e1 = __builtin_amdgcn_exp2f(st[nk][nq][1]);
        float e2 = __builtin_amdgcn_exp2f(st[nk][nq][2]);
        float e3 = __builtin_amdgcn_exp2f(st[nk][nq][3]);
        union { bf16 hh[4]; uint2 dd; } pk;
        pk.hh[0] = (bf16)e0; pk.hh[1] = (bf16)e1;
        pk.hh[2] = (bf16)e2; pk.hh[3] = (bf16)e3;
        uint2 lw = nq ? (nk ? lm11 : lm10) : (nk ? lm01 : lm00);
        pk.dd.x &= lw.x;
        pk.dd.y &= lw.y;
        *(uint2*)(sPw + pwo[nk] + nq * 1024) = pk.dd;
      }
    }

    // PV: O^T[d][q] += Vt . P^T ; denominator via mfma(ones, P)
    __builtin_amdgcn_s_setprio(1);
    {
      bf16x8 pf0 = *(const bf16x8*)(sPw + pr_off);
      bf16x8 pf1 = *(const bf16x8*)(sPw + pr_off + 1024);
      dacc[0] = __builtin_amdgcn_mfma_f32_16x16x32_bf16(onesv, pf0, dacc[0], 0, 0, 0);
      dacc[1] = __builtin_amdgcn_mfma_f32_16x16x32_bf16(onesv, pf1, dacc[1], 0, 0, 0);
#pragma unroll
      for (int md = 0; md < 4; ++md) {
        bf16x8 vf = *(const bf16x8*)(kbuf + 4096 + pr_off + md * 1024);
        oacc[md][0] = __builtin_amdgcn_mfma_f32_16x16x32_bf16(vf, pf0, oacc[md][0], 0, 0, 0);
        oacc[md][1] = __builtin_amdgcn_mfma_f32_16x16x32_bf16(vf, pf1, oacc[md][1], 0, 0, 0);
      }
    }
    __builtin_amdgcn_s_setprio(0);

    if (t < 63) {
      char* nbuf = sKV + (((t + 1) & 1) << 13);
      *(uint4*)(nbuf + dK) = kr;
      *(uint4*)(nbuf + dV) = vr;
    }
    mw0 = mn0; mw1 = mn1;
  }

  float inv0 = 1.f / dacc[0][0];
  float inv1 = 1.f / dacc[1][0];

  // epilogue: O^T -> LDS transpose -> coalesced bf16 write
  __syncthreads();
  char* Xl = smem;
#pragma unroll
  for (int nq = 0; nq < 2; ++nq) {
    float inv = nq ? inv1 : inv0;
    int ql = w * 32 + nq * 16 + c;
#pragma unroll
    for (int md = 0; md < 4; ++md)
#pragma unroll
      for (int r = 0; r < 4; ++r) {
        int d = md * 16 + g * 4 + r;
        int blk = d >> 3, off = d & 7;
        *(bf16*)(Xl + ql * 128 + ((blk ^ (ql & 7)) << 4) + off * 2) =
            (bf16)(oacc[md][nq][r] * inv);
      }
  }
  __syncthreads();
#pragma unroll
  for (int i = 0; i < 4; ++i) {
    int u = i * 256 + tid;
    int row = u >> 3, blk = u & 7;
    uint4 xv = *(const uint4*)(Xl + row * 128 + ((blk ^ (row & 7)) << 4));
    *(uint4*)&X[(size_t)(b * 2048 + q0 + row) * 1024 + h * 64 + blk * 8] = xv;
  }
}

// ---------------- launch ----------------

extern "C" void kernel_launch(void* const* d_in, const int* in_sizes, int n_in,
                              void* d_out, int out_size, void* d_ws, size_t ws_size,
                              hipStream_t stream) {
  const float* q    = (const float*)d_in[0];
  const float* k    = (const float*)d_in[1];
  const float* v    = (const float*)d_in[2];
  const int*   mask = (const int*)d_in[3];
  const float* Wq   = (const float*)d_in[4];
  const float* Wk   = (const float*)d_in[5];
  const float* Wv   = (const float*)d_in[6];
  const float* Wo   = (const float*)d_in[7];
  const float* Wb   = (const float*)d_in[8];

  char* ws = (char*)d_ws;
  bf16* qkv = (bf16*)(ws + 0);             // qb|kb|vb contiguous, 48 MB
  bf16* Wt  = (bf16*)(ws + 50331648);      // 8 MB (4 packed 1024x1024)
  bf16* Qp  = (bf16*)(ws + 58720256);
  bf16* Kp  = (bf16*)(ws + 75497472);
  bf16* Vt  = (bf16*)(ws + 92274688);
  bf16* Xb  = (bf16*)(ws + 109051904);
  u32*  mb  = (u32*) (ws + 125829120);     // 2 MB bitmask

  prep<<<dim3(2048, 1, 5), 256, 0, stream>>>(q, k, v, mask, Wq, Wk, Wv, Wo, qkv, Wt, mb);

  proj_fused<<<dim3(1536, 1, 1), 256, 0, stream>>>(qkv, Wt, Qp, Kp, Vt);

  attn_fwd<<<dim3(16, 64, 1), 256, 0, stream>>>(Qp, Kp, Vt, mb, Xb);

  gemm_out<<<dim3(8, 64, 1), 256, 0, stream>>>(Xb, Wt + 3145728, (float*)d_out, Wb);
}